// Round 1
// baseline (1959.289 us; speedup 1.0000x reference)
//
#include <hip/hip_runtime.h>

// Problem constants (B=1024, C=1024, H=W=8 -> HW=64, 16 heads, hd=64)
#define BATCH 1024
#define CH    1024
#define HW    64
#define NHEAD 16
#define HDIM  64
#define PIX   (BATCH*HW)          // 65536
#define KDIM  1024
#define LN_EPS 1e-5f
#define NORM_EPS 1e-12f
#define TEMP_EPS 1e-6f

typedef __bf16 bf16;
typedef __bf16 bf16x8 __attribute__((ext_vector_type(8)));
typedef float  f32x4  __attribute__((ext_vector_type(4)));

// ---------------- prep kernels ----------------

__global__ void cvt_f32_bf16(const float* __restrict__ src, bf16* __restrict__ dst, int n) {
    int i = blockIdx.x * 256 + threadIdx.x;
    if (i < n) dst[i] = (bf16)src[i];
}

__global__ void pack_bias(const float* __restrict__ bq, const float* __restrict__ bk,
                          const float* __restrict__ bv, float* __restrict__ dst) {
    int i = blockIdx.x * 256 + threadIdx.x;
    if (i < 1024)      dst[i] = bq[i];
    else if (i < 2048) dst[i] = bk[i - 1024];
    else if (i < 3072) dst[i] = bv[i - 2048];
}

// x[b][c][hw] fp32 -> xT[pix][c] bf16  (pix = b*64+hw), LDS transpose, both sides coalesced
__global__ void transpose_x(const float* __restrict__ x, bf16* __restrict__ xT) {
    __shared__ float tile[32][65];
    int b = blockIdx.y, ct = blockIdx.x, t = threadIdx.x;
    const float* xb = x + (size_t)b * (CH*HW) + (size_t)ct * 32 * HW;
    for (int it = 0; it < 8; ++it) {
        int cl = (t >> 6) + it * 4;
        int hw = t & 63;
        tile[cl][hw] = xb[cl * HW + hw];
    }
    __syncthreads();
    bf16* dst = xT + (size_t)b * HW * KDIM + ct * 32;
    for (int it = 0; it < 8; ++it) {
        int hw = (t >> 5) + it * 8;
        int cl = t & 31;
        dst[(size_t)hw * KDIM + cl] = (bf16)tile[cl][hw];
    }
}

// ---------------- GEMM: qkv = Wqkv (3072x1024) x xT^T, out [pix][3072] bf16 ----------------
// D[pix][o] = sum_k xT[pix][k] * W[o][k] + bias[o]
// 128x128 tile, BK=64, 256 threads (4 waves), each wave 64x64 (4x4 16x16x32 MFMA tiles)

__global__ __launch_bounds__(256) void gemm_qkv(const bf16* __restrict__ A,  // xT [PIX][1024]
                                                const bf16* __restrict__ W,  // [3072][1024]
                                                const float* __restrict__ bias,
                                                bf16* __restrict__ out) {    // [PIX][3072]
    __shared__ bf16 As[128][72];
    __shared__ bf16 Bs[128][72];
    const int t = threadIdx.x;
    const int o0 = blockIdx.x * 128;     // over 3072 (24 tiles)
    const int pix0 = blockIdx.y * 128;   // over 65536 (512 tiles)
    const int w = t >> 6, lane = t & 63, quad = lane >> 4, ln = lane & 15;
    const int wm = w & 1, wn = w >> 1;

    f32x4 acc[4][4];
    for (int i = 0; i < 4; ++i)
        for (int j = 0; j < 4; ++j)
            acc[i][j] = (f32x4){0.f, 0.f, 0.f, 0.f};

    for (int kk = 0; kk < KDIM; kk += 64) {
        __syncthreads();
        for (int it = 0; it < 4; ++it) {
            int idx = t + 256 * it;
            int row = idx >> 3, ch = idx & 7;
            *(uint4*)&As[row][ch * 8] = *(const uint4*)&A[(size_t)(pix0 + row) * KDIM + kk + ch * 8];
            *(uint4*)&Bs[row][ch * 8] = *(const uint4*)&W[(size_t)(o0 + row) * KDIM + kk + ch * 8];
        }
        __syncthreads();
        bf16x8 af[4][2], bb[4][2];
        for (int tm = 0; tm < 4; ++tm)
            for (int ks = 0; ks < 2; ++ks)
                af[tm][ks] = *(const bf16x8*)&As[64 * wm + 16 * tm + ln][ks * 32 + quad * 8];
        for (int tn = 0; tn < 4; ++tn)
            for (int ks = 0; ks < 2; ++ks)
                bb[tn][ks] = *(const bf16x8*)&Bs[64 * wn + 16 * tn + ln][ks * 32 + quad * 8];
        for (int tm = 0; tm < 4; ++tm)
            for (int tn = 0; tn < 4; ++tn) {
                acc[tm][tn] = __builtin_amdgcn_mfma_f32_16x16x32_bf16(af[tm][0], bb[tn][0], acc[tm][tn], 0, 0, 0);
                acc[tm][tn] = __builtin_amdgcn_mfma_f32_16x16x32_bf16(af[tm][1], bb[tn][1], acc[tm][tn], 0, 0, 0);
            }
    }
    float bv[4];
    for (int tn = 0; tn < 4; ++tn) bv[tn] = bias[o0 + 64 * wn + 16 * tn + ln];
    for (int tm = 0; tm < 4; ++tm)
        for (int r = 0; r < 4; ++r) {
            int row = pix0 + 64 * wm + 16 * tm + quad * 4 + r;
            for (int tn = 0; tn < 4; ++tn) {
                int col = o0 + 64 * wn + 16 * tn + ln;
                out[(size_t)row * 3072 + col] = (bf16)(acc[tm][tn][r] + bv[tn]);
            }
        }
}

// ---------------- attention per (b, h) ----------------
// qkv layout: [pix][3072]  (q: cols h*64+d, k: 1024+h*64+d, v: 2048+h*64+d)
// normalize q,k over spatial dim n; attn = softmax((q.k)/(T+eps)); out[n][d] -> attnout[pix][c]

__global__ __launch_bounds__(256) void attn_kernel(const bf16* __restrict__ qkv,
                                                   bf16* __restrict__ attnout,
                                                   const float* __restrict__ temp) {
    __shared__ bf16 qs[64][72];
    __shared__ bf16 ksld[64][72];
    __shared__ bf16 vs[64][72];   // transposed: vs[d][m]
    __shared__ bf16 ps[64][72];   // softmax probs [n][m]
    __shared__ float rsq[64], rsk[64];

    int h = blockIdx.x, b = blockIdx.y, t = threadIdx.x;
    int w = t >> 6, lane = t & 63, quad = lane >> 4, ln = lane & 15;
    const bf16* base = qkv + (size_t)b * HW * 3072 + h * HDIM;

    // stage q, k: rows = spatial n, cols = d (contiguous)
    for (int it = 0; it < 2; ++it) {
        int row = (t >> 3) + it * 32, ch = t & 7;
        *(uint4*)&qs[row][ch * 8]   = *(const uint4*)&base[(size_t)row * 3072 + ch * 8];
        *(uint4*)&ksld[row][ch * 8] = *(const uint4*)&base[(size_t)row * 3072 + 1024 + ch * 8];
    }
    // stage v transposed -> vs[d][m]
    for (int it = 0; it < 2; ++it) {
        int m = t & 63, dg = (t >> 6) * 8 + it * 32;
        uint4 v4 = *(const uint4*)&base[(size_t)m * 3072 + 2048 + dg];
        bf16 tmpv[8];
        *(uint4*)tmpv = v4;
        for (int j = 0; j < 8; ++j) vs[dg + j][m] = tmpv[j];
    }
    __syncthreads();

    // l2 norms over n (rows) for each d
    if (t < 128) {
        int d = t & 63;
        float ss = 0.f;
        if (t < 64) {
            for (int n = 0; n < 64; ++n) { float v = (float)qs[n][d]; ss += v * v; }
            rsq[d] = 1.0f / fmaxf(sqrtf(ss), NORM_EPS);
        } else {
            for (int n = 0; n < 64; ++n) { float v = (float)ksld[n][d]; ss += v * v; }
            rsk[d] = 1.0f / fmaxf(sqrtf(ss), NORM_EPS);
        }
    }
    __syncthreads();
    for (int it = 0; it < 16; ++it) {
        int e = t + 256 * it;
        int n = e >> 6, d = e & 63;
        qs[n][d]   = (bf16)((float)qs[n][d] * rsq[d]);
        ksld[n][d] = (bf16)((float)ksld[n][d] * rsk[d]);
    }
    __syncthreads();

    // QK^T: attn[n][m] = sum_d q[d][n] k[d][m];  wave w -> rows n in [16w,16w+16)
    f32x4 acc[4];
    for (int i = 0; i < 4; ++i) acc[i] = (f32x4){0.f, 0.f, 0.f, 0.f};
    bf16x8 aq[2];
    for (int ks = 0; ks < 2; ++ks)
        aq[ks] = *(const bf16x8*)&qs[16 * w + ln][ks * 32 + quad * 8];
    for (int tn = 0; tn < 4; ++tn)
        for (int ks = 0; ks < 2; ++ks) {
            bf16x8 bk = *(const bf16x8*)&ksld[16 * tn + ln][ks * 32 + quad * 8];
            acc[tn] = __builtin_amdgcn_mfma_f32_16x16x32_bf16(aq[ks], bk, acc[tn], 0, 0, 0);
        }

    float invt = 1.0f / (temp[0] + TEMP_EPS);
    for (int r = 0; r < 4; ++r) {
        float v[4];
        for (int tn = 0; tn < 4; ++tn) v[tn] = acc[tn][r] * invt;
        float mx = fmaxf(fmaxf(v[0], v[1]), fmaxf(v[2], v[3]));
        for (int mask = 1; mask < 16; mask <<= 1) mx = fmaxf(mx, __shfl_xor(mx, mask));
        float p[4], s = 0.f;
        for (int tn = 0; tn < 4; ++tn) { p[tn] = __expf(v[tn] - mx); s += p[tn]; }
        for (int mask = 1; mask < 16; mask <<= 1) s += __shfl_xor(s, mask);
        float inv = 1.0f / s;
        int n = 16 * w + quad * 4 + r;
        for (int tn = 0; tn < 4; ++tn)
            ps[n][16 * tn + ln] = (bf16)(p[tn] * inv);
    }
    __syncthreads();

    // PV: out[n][d] = sum_m attn[n][m] v[d][m]
    f32x4 acc2[4];
    for (int i = 0; i < 4; ++i) acc2[i] = (f32x4){0.f, 0.f, 0.f, 0.f};
    bf16x8 ap[2];
    for (int ks = 0; ks < 2; ++ks)
        ap[ks] = *(const bf16x8*)&ps[16 * w + ln][ks * 32 + quad * 8];
    for (int tn = 0; tn < 4; ++tn)
        for (int ks = 0; ks < 2; ++ks) {
            bf16x8 bv = *(const bf16x8*)&vs[16 * tn + ln][ks * 32 + quad * 8];
            acc2[tn] = __builtin_amdgcn_mfma_f32_16x16x32_bf16(ap[ks], bv, acc2[tn], 0, 0, 0);
        }

    // store: attnout[(b*64+n)*1024 + h*64 + d]
    bf16* dst = attnout + (size_t)b * HW * CH + h * HDIM;
    for (int r = 0; r < 4; ++r) {
        int n = 16 * w + quad * 4 + r;
        for (int tn = 0; tn < 4; ++tn)
            dst[(size_t)n * CH + 16 * tn + ln] = (bf16)acc2[tn][r];
    }
}

// ---------------- proj GEMM + bias + gamma blend + LN partial stats ----------------
// D[pix][o] = sum_c AO[pix][c] * Wp[o][c]; v = g*(D+bp) + (1-g)*x; stats[b] += (sum, sumsq)

__global__ __launch_bounds__(256) void gemm_proj(const bf16* __restrict__ AO,   // [PIX][1024]
                                                 const bf16* __restrict__ Wp,   // [1024][1024]
                                                 const float* __restrict__ bp,
                                                 const float* __restrict__ x,   // [B][C][HW] fp32
                                                 const float* __restrict__ gamma,
                                                 float* __restrict__ out_ws,    // [PIX][1024]
                                                 float* __restrict__ stats) {   // [B][2]
    __shared__ bf16 As[128][72];
    __shared__ bf16 Bs[128][72];
    const int t = threadIdx.x;
    const int o0 = blockIdx.x * 128;    // over 1024 (8 tiles)
    const int pix0 = blockIdx.y * 128;  // over 65536 (512 tiles)
    const int w = t >> 6, lane = t & 63, quad = lane >> 4, ln = lane & 15;
    const int wm = w & 1, wn = w >> 1;

    f32x4 acc[4][4];
    for (int i = 0; i < 4; ++i)
        for (int j = 0; j < 4; ++j)
            acc[i][j] = (f32x4){0.f, 0.f, 0.f, 0.f};

    for (int kk = 0; kk < KDIM; kk += 64) {
        __syncthreads();
        for (int it = 0; it < 4; ++it) {
            int idx = t + 256 * it;
            int row = idx >> 3, ch = idx & 7;
            *(uint4*)&As[row][ch * 8] = *(const uint4*)&AO[(size_t)(pix0 + row) * KDIM + kk + ch * 8];
            *(uint4*)&Bs[row][ch * 8] = *(const uint4*)&Wp[(size_t)(o0 + row) * KDIM + kk + ch * 8];
        }
        __syncthreads();
        bf16x8 af[4][2], bb[4][2];
        for (int tm = 0; tm < 4; ++tm)
            for (int ks = 0; ks < 2; ++ks)
                af[tm][ks] = *(const bf16x8*)&As[64 * wm + 16 * tm + ln][ks * 32 + quad * 8];
        for (int tn = 0; tn < 4; ++tn)
            for (int ks = 0; ks < 2; ++ks)
                bb[tn][ks] = *(const bf16x8*)&Bs[64 * wn + 16 * tn + ln][ks * 32 + quad * 8];
        for (int tm = 0; tm < 4; ++tm)
            for (int tn = 0; tn < 4; ++tn) {
                acc[tm][tn] = __builtin_amdgcn_mfma_f32_16x16x32_bf16(af[tm][0], bb[tn][0], acc[tm][tn], 0, 0, 0);
                acc[tm][tn] = __builtin_amdgcn_mfma_f32_16x16x32_bf16(af[tm][1], bb[tn][1], acc[tm][tn], 0, 0, 0);
            }
    }

    float g = gamma[0];
    float bv[4];
    for (int tn = 0; tn < 4; ++tn) bv[tn] = bp[o0 + 64 * wn + 16 * tn + ln];
    int bidx = (pix0 + 64 * wm) >> 6;   // wave's 64 pix rows are one batch
    float sum = 0.f, ss = 0.f;
    for (int tm = 0; tm < 4; ++tm)
        for (int r = 0; r < 4; ++r) {
            int pixr = pix0 + 64 * wm + 16 * tm + quad * 4 + r;
            int hw = pixr & 63;
            for (int tn = 0; tn < 4; ++tn) {
                int col = o0 + 64 * wn + 16 * tn + ln;
                float v = acc[tm][tn][r] + bv[tn];
                float res = x[((size_t)bidx * CH + col) * HW + hw];
                v = g * v + (1.0f - g) * res;
                out_ws[(size_t)pixr * CH + col] = v;
                sum += v;
                ss += v * v;
            }
        }
    for (int mask = 1; mask < 64; mask <<= 1) {
        sum += __shfl_xor(sum, mask);
        ss  += __shfl_xor(ss, mask);
    }
    if (lane == 0) {
        atomicAdd(&stats[2 * bidx], sum);
        atomicAdd(&stats[2 * bidx + 1], ss);
    }
}

// ---------------- LayerNorm finalize ----------------
__global__ void ln_kernel(const float* __restrict__ out_ws, const float* __restrict__ stats,
                          const float* __restrict__ lnw, const float* __restrict__ lnb,
                          float* __restrict__ y) {
    const size_t total = (size_t)BATCH * CH * HW;
    const float invN = 1.0f / (float)(CH * HW);
    for (size_t i = (size_t)blockIdx.x * 256 + threadIdx.x; i < total; i += (size_t)gridDim.x * 256) {
        int b = (int)(i >> 16);
        int rem = (int)(i & 65535);
        int c = rem >> 6;
        int hw = rem & 63;
        float mean = stats[2 * b] * invN;
        float var = stats[2 * b + 1] * invN - mean * mean;
        float rstd = rsqrtf(var + LN_EPS);
        float v = out_ws[((size_t)(b * HW + hw)) * CH + c];
        y[i] = (v - mean) * rstd * lnw[rem] + lnb[rem];
    }
}

// ---------------- launch ----------------
extern "C" void kernel_launch(void* const* d_in, const int* in_sizes, int n_in,
                              void* d_out, int out_size, void* d_ws, size_t ws_size,
                              hipStream_t stream) {
    const float* x     = (const float*)d_in[0];
    const float* Wq    = (const float*)d_in[1];
    const float* bq    = (const float*)d_in[2];
    const float* Wk    = (const float*)d_in[3];
    const float* bk    = (const float*)d_in[4];
    const float* Wv    = (const float*)d_in[5];
    const float* bv    = (const float*)d_in[6];
    const float* Wp    = (const float*)d_in[7];
    const float* bp    = (const float*)d_in[8];
    const float* gamma = (const float*)d_in[9];
    const float* temp  = (const float*)d_in[10];
    const float* lnw   = (const float*)d_in[11];
    const float* lnb   = (const float*)d_in[12];
    float* y = (float*)d_out;

    char* ws = (char*)d_ws;
    // workspace layout (bytes)
    const size_t off_wqkv = 0;                               // 3072*1024*2 = 6291456
    const size_t off_wp   = 6291456;                         // 1024*1024*2 = 2097152
    const size_t off_bias = off_wp + 2097152;                // 3072*4 = 12288
    const size_t off_stat = off_bias + 12288;                // 1024*2*4 = 8192
    const size_t off_xT   = off_stat + 8192;                 // 65536*1024*2 = 134217728
    const size_t off_qkv  = off_xT + 134217728;              // 65536*3072*2 = 402653184
    const size_t off_ao   = off_qkv + 402653184;             // 65536*1024*2 = 134217728
    const size_t off_out  = off_qkv;                         // alias: qkv dead after attention

    bf16*  wqkv_b = (bf16*)(ws + off_wqkv);
    bf16*  wp_b   = (bf16*)(ws + off_wp);
    float* bias_q = (float*)(ws + off_bias);
    float* stats  = (float*)(ws + off_stat);
    bf16*  xT     = (bf16*)(ws + off_xT);
    bf16*  qkv    = (bf16*)(ws + off_qkv);
    bf16*  ao     = (bf16*)(ws + off_ao);
    float* out_ws = (float*)(ws + off_out);

    const int wn = 1024 * 1024;
    cvt_f32_bf16<<<4096, 256, 0, stream>>>(Wq, wqkv_b, wn);
    cvt_f32_bf16<<<4096, 256, 0, stream>>>(Wk, wqkv_b + (size_t)wn, wn);
    cvt_f32_bf16<<<4096, 256, 0, stream>>>(Wv, wqkv_b + (size_t)2 * wn, wn);
    cvt_f32_bf16<<<4096, 256, 0, stream>>>(Wp, wp_b, wn);
    pack_bias<<<12, 256, 0, stream>>>(bq, bk, bv, bias_q);
    transpose_x<<<dim3(32, 1024), 256, 0, stream>>>(x, xT);
    gemm_qkv<<<dim3(24, 512), 256, 0, stream>>>(xT, wqkv_b, bias_q, qkv);
    attn_kernel<<<dim3(16, 1024), 256, 0, stream>>>(qkv, ao, temp);
    hipMemsetAsync(stats, 0, 8192, stream);
    gemm_proj<<<dim3(8, 512), 256, 0, stream>>>(ao, wp_b, bp, x, gamma, out_ws, stats);
    ln_kernel<<<32768, 256, 0, stream>>>(out_ws, stats, lnw, lnb, y);
}

// Round 2
// 1808.208 us; speedup vs baseline: 1.0836x; 1.0836x over previous
//
#include <hip/hip_runtime.h>

// Problem constants (B=1024, C=1024, H=W=8 -> HW=64, 16 heads, hd=64)
#define BATCH 1024
#define CH    1024
#define HW    64
#define NHEAD 16
#define HDIM  64
#define PIX   (BATCH*HW)          // 65536
#define KDIM  1024
#define LN_EPS 1e-5f
#define NORM_EPS 1e-12f
#define TEMP_EPS 1e-6f

typedef __bf16 bf16;
typedef __bf16 bf16x8 __attribute__((ext_vector_type(8)));
typedef float  f32x4  __attribute__((ext_vector_type(4)));

// async global->LDS 16B copy: LDS dest is wave-uniform base + lane*16
__device__ __forceinline__ void async_copy16(bf16* lds, const bf16* g) {
    __builtin_amdgcn_global_load_lds((const __attribute__((address_space(1))) void*)g,
                                     (__attribute__((address_space(3))) void*)lds, 16, 0, 0);
}

// ---------------- prep kernels ----------------

__global__ void cvt_f32_bf16(const float* __restrict__ src, bf16* __restrict__ dst, int n) {
    int i = blockIdx.x * 256 + threadIdx.x;
    if (i < n) dst[i] = (bf16)src[i];
}

__global__ void pack_bias(const float* __restrict__ bq, const float* __restrict__ bk,
                          const float* __restrict__ bv, float* __restrict__ dst) {
    int i = blockIdx.x * 256 + threadIdx.x;
    if (i < 1024)      dst[i] = bq[i];
    else if (i < 2048) dst[i] = bk[i - 1024];
    else if (i < 3072) dst[i] = bv[i - 2048];
}

// x[b][c][hw] fp32 -> xT[pix][c] bf16  (pix = b*64+hw), LDS transpose, both sides coalesced
__global__ void transpose_x(const float* __restrict__ x, bf16* __restrict__ xT) {
    __shared__ float tile[32][65];
    int b = blockIdx.y, ct = blockIdx.x, t = threadIdx.x;
    const float* xb = x + (size_t)b * (CH*HW) + (size_t)ct * 32 * HW;
    for (int it = 0; it < 8; ++it) {
        int cl = (t >> 6) + it * 4;
        int hw = t & 63;
        tile[cl][hw] = xb[cl * HW + hw];
    }
    __syncthreads();
    bf16* dst = xT + (size_t)b * HW * KDIM + ct * 32;
    for (int it = 0; it < 8; ++it) {
        int hw = (t >> 5) + it * 8;
        int cl = t & 31;
        dst[(size_t)hw * KDIM + cl] = (bf16)tile[cl][hw];
    }
}

// ---------------- GEMM: qkv = Wqkv (3072x1024) x xT^T, out [pix][3072] bf16 ----------------
// D[pix][o] = sum_k xT[pix][k] * W[o][k] + bias[o]
// 128x128 tile, BK=64, 256 threads (4 waves), each wave 64x64 (4x4 16x16x32 MFMA tiles)
// LDS: unpadded [128][64] bf16, 16B chunks XOR-swizzled: chunk c of row r at slot c^(r&7).
// Staged via global_load_lds width=16 (lane loads the pre-permuted global chunk).

__global__ __launch_bounds__(256) void gemm_qkv(const bf16* __restrict__ A,  // xT [PIX][1024]
                                                const bf16* __restrict__ W,  // [3072][1024]
                                                const float* __restrict__ bias,
                                                bf16* __restrict__ out) {    // [PIX][3072]
    __shared__ bf16 As[128 * 64];
    __shared__ bf16 Bs[128 * 64];
    const int t = threadIdx.x;
    const int o0 = blockIdx.x * 128;     // over 3072 (24 tiles)
    const int pix0 = blockIdx.y * 128;   // over 65536 (512 tiles)
    const int w = t >> 6, lane = t & 63, quad = lane >> 4, ln = lane & 15;
    const int wm = w & 1, wn = w >> 1;
    const int sw = ln & 7;               // row&7 for all fragment rows this lane reads

    f32x4 acc[4][4];
    for (int i = 0; i < 4; ++i)
        for (int j = 0; j < 4; ++j)
            acc[i][j] = (f32x4){0.f, 0.f, 0.f, 0.f};

    for (int kk = 0; kk < KDIM; kk += 64) {
        __syncthreads();
        const bf16* gA = A + (size_t)pix0 * KDIM + kk;
        const bf16* gB = W + (size_t)o0 * KDIM + kk;
        for (int it = 0; it < 4; ++it) {
            int s = (w * 4 + it) * 64 + lane;     // linear 16B-chunk slot 0..1023
            int row = s >> 3;
            int c = (s & 7) ^ (row & 7);          // global chunk whose data lives at slot s
            bf16* ldsbase = &As[(size_t)(w * 4 + it) * 64 * 8];  // wave-uniform
            async_copy16(ldsbase, gA + (size_t)row * KDIM + c * 8);
            bf16* ldsbaseB = &Bs[(size_t)(w * 4 + it) * 64 * 8];
            async_copy16(ldsbaseB, gB + (size_t)row * KDIM + c * 8);
        }
        __syncthreads();
        bf16x8 af[4][2], bb[4][2];
        for (int tm = 0; tm < 4; ++tm)
            for (int ks = 0; ks < 2; ++ks) {
                int r = 64 * wm + 16 * tm + ln;
                af[tm][ks] = *(const bf16x8*)&As[r * 64 + (((ks * 4 + quad) ^ sw) * 8)];
            }
        for (int tn = 0; tn < 4; ++tn)
            for (int ks = 0; ks < 2; ++ks) {
                int r = 64 * wn + 16 * tn + ln;
                bb[tn][ks] = *(const bf16x8*)&Bs[r * 64 + (((ks * 4 + quad) ^ sw) * 8)];
            }
        for (int tm = 0; tm < 4; ++tm)
            for (int tn = 0; tn < 4; ++tn) {
                acc[tm][tn] = __builtin_amdgcn_mfma_f32_16x16x32_bf16(af[tm][0], bb[tn][0], acc[tm][tn], 0, 0, 0);
                acc[tm][tn] = __builtin_amdgcn_mfma_f32_16x16x32_bf16(af[tm][1], bb[tn][1], acc[tm][tn], 0, 0, 0);
            }
    }
    float bv[4];
    for (int tn = 0; tn < 4; ++tn) bv[tn] = bias[o0 + 64 * wn + 16 * tn + ln];
    for (int tm = 0; tm < 4; ++tm)
        for (int r = 0; r < 4; ++r) {
            int row = pix0 + 64 * wm + 16 * tm + quad * 4 + r;
            for (int tn = 0; tn < 4; ++tn) {
                int col = o0 + 64 * wn + 16 * tn + ln;
                out[(size_t)row * 3072 + col] = (bf16)(acc[tm][tn][r] + bv[tn]);
            }
        }
}

// ---------------- attention per (b, h) ----------------
// qkv layout: [pix][3072]  (q: cols h*64+d, k: 1024+h*64+d, v: 2048+h*64+d)
// normalize q,k over spatial dim n; attn = softmax((q.k)/(T+eps)); out[n][d] -> attnout[pix][c]

__global__ __launch_bounds__(256) void attn_kernel(const bf16* __restrict__ qkv,
                                                   bf16* __restrict__ attnout,
                                                   const float* __restrict__ temp) {
    __shared__ bf16 qs[64][72];
    __shared__ bf16 ksld[64][72];
    __shared__ bf16 vs[64][72];   // transposed: vs[d][m]
    __shared__ bf16 ps[64][72];   // softmax probs [n][m]
    __shared__ float rsq[64], rsk[64];

    int h = blockIdx.x, b = blockIdx.y, t = threadIdx.x;
    int w = t >> 6, lane = t & 63, quad = lane >> 4, ln = lane & 15;
    const bf16* base = qkv + (size_t)b * HW * 3072 + h * HDIM;

    // stage q, k: rows = spatial n, cols = d (contiguous)
    for (int it = 0; it < 2; ++it) {
        int row = (t >> 3) + it * 32, ch = t & 7;
        *(uint4*)&qs[row][ch * 8]   = *(const uint4*)&base[(size_t)row * 3072 + ch * 8];
        *(uint4*)&ksld[row][ch * 8] = *(const uint4*)&base[(size_t)row * 3072 + 1024 + ch * 8];
    }
    // stage v transposed -> vs[d][m]
    for (int it = 0; it < 2; ++it) {
        int m = t & 63, dg = (t >> 6) * 8 + it * 32;
        uint4 v4 = *(const uint4*)&base[(size_t)m * 3072 + 2048 + dg];
        bf16 tmpv[8];
        *(uint4*)tmpv = v4;
        for (int j = 0; j < 8; ++j) vs[dg + j][m] = tmpv[j];
    }
    __syncthreads();

    // l2 norms over n (rows) for each d
    if (t < 128) {
        int d = t & 63;
        float ss = 0.f;
        if (t < 64) {
            for (int n = 0; n < 64; ++n) { float v = (float)qs[n][d]; ss += v * v; }
            rsq[d] = 1.0f / fmaxf(sqrtf(ss), NORM_EPS);
        } else {
            for (int n = 0; n < 64; ++n) { float v = (float)ksld[n][d]; ss += v * v; }
            rsk[d] = 1.0f / fmaxf(sqrtf(ss), NORM_EPS);
        }
    }
    __syncthreads();
    for (int it = 0; it < 16; ++it) {
        int e = t + 256 * it;
        int n = e >> 6, d = e & 63;
        qs[n][d]   = (bf16)((float)qs[n][d] * rsq[d]);
        ksld[n][d] = (bf16)((float)ksld[n][d] * rsk[d]);
    }
    __syncthreads();

    // QK^T: attn[n][m] = sum_d q[d][n] k[d][m];  wave w -> rows n in [16w,16w+16)
    f32x4 acc[4];
    for (int i = 0; i < 4; ++i) acc[i] = (f32x4){0.f, 0.f, 0.f, 0.f};
    bf16x8 aq[2];
    for (int ks = 0; ks < 2; ++ks)
        aq[ks] = *(const bf16x8*)&qs[16 * w + ln][ks * 32 + quad * 8];
    for (int tn = 0; tn < 4; ++tn)
        for (int ks = 0; ks < 2; ++ks) {
            bf16x8 bk = *(const bf16x8*)&ksld[16 * tn + ln][ks * 32 + quad * 8];
            acc[tn] = __builtin_amdgcn_mfma_f32_16x16x32_bf16(aq[ks], bk, acc[tn], 0, 0, 0);
        }

    float invt = 1.0f / (temp[0] + TEMP_EPS);
    for (int r = 0; r < 4; ++r) {
        float v[4];
        for (int tn = 0; tn < 4; ++tn) v[tn] = acc[tn][r] * invt;
        float mx = fmaxf(fmaxf(v[0], v[1]), fmaxf(v[2], v[3]));
        for (int mask = 1; mask < 16; mask <<= 1) mx = fmaxf(mx, __shfl_xor(mx, mask));
        float p[4], s = 0.f;
        for (int tn = 0; tn < 4; ++tn) { p[tn] = __expf(v[tn] - mx); s += p[tn]; }
        for (int mask = 1; mask < 16; mask <<= 1) s += __shfl_xor(s, mask);
        float inv = 1.0f / s;
        int n = 16 * w + quad * 4 + r;
        for (int tn = 0; tn < 4; ++tn)
            ps[n][16 * tn + ln] = (bf16)(p[tn] * inv);
    }
    __syncthreads();

    // PV: out[n][d] = sum_m attn[n][m] v[d][m]
    f32x4 acc2[4];
    for (int i = 0; i < 4; ++i) acc2[i] = (f32x4){0.f, 0.f, 0.f, 0.f};
    bf16x8 ap[2];
    for (int ks = 0; ks < 2; ++ks)
        ap[ks] = *(const bf16x8*)&ps[16 * w + ln][ks * 32 + quad * 8];
    for (int tn = 0; tn < 4; ++tn)
        for (int ks = 0; ks < 2; ++ks) {
            bf16x8 bv = *(const bf16x8*)&vs[16 * tn + ln][ks * 32 + quad * 8];
            acc2[tn] = __builtin_amdgcn_mfma_f32_16x16x32_bf16(ap[ks], bv, acc2[tn], 0, 0, 0);
        }

    // store: attnout[(b*64+n)*1024 + h*64 + d]
    bf16* dst = attnout + (size_t)b * HW * CH + h * HDIM;
    for (int r = 0; r < 4; ++r) {
        int n = 16 * w + quad * 4 + r;
        for (int tn = 0; tn < 4; ++tn)
            dst[(size_t)n * CH + 16 * tn + ln] = (bf16)acc2[tn][r];
    }
}

// ---------------- proj GEMM + bias + gamma blend + LN partial stats ----------------
// D[pix][o] = sum_c AO[pix][c] * Wp[o][c]; v = g*(D+bp) + (1-g)*x; stats[b] += (sum, sumsq)

__global__ __launch_bounds__(256) void gemm_proj(const bf16* __restrict__ AO,   // [PIX][1024]
                                                 const bf16* __restrict__ Wp,   // [1024][1024]
                                                 const float* __restrict__ bp,
                                                 const float* __restrict__ x,   // [B][C][HW] fp32
                                                 const float* __restrict__ gamma,
                                                 float* __restrict__ out_ws,    // [PIX][1024]
                                                 float* __restrict__ stats) {   // [B][2]
    __shared__ bf16 As[128 * 64];
    __shared__ bf16 Bs[128 * 64];
    const int t = threadIdx.x;
    const int o0 = blockIdx.x * 128;    // over 1024 (8 tiles)
    const int pix0 = blockIdx.y * 128;  // over 65536 (512 tiles)
    const int w = t >> 6, lane = t & 63, quad = lane >> 4, ln = lane & 15;
    const int wm = w & 1, wn = w >> 1;
    const int sw = ln & 7;

    f32x4 acc[4][4];
    for (int i = 0; i < 4; ++i)
        for (int j = 0; j < 4; ++j)
            acc[i][j] = (f32x4){0.f, 0.f, 0.f, 0.f};

    for (int kk = 0; kk < KDIM; kk += 64) {
        __syncthreads();
        const bf16* gA = AO + (size_t)pix0 * KDIM + kk;
        const bf16* gB = Wp + (size_t)o0 * KDIM + kk;
        for (int it = 0; it < 4; ++it) {
            int s = (w * 4 + it) * 64 + lane;
            int row = s >> 3;
            int c = (s & 7) ^ (row & 7);
            bf16* ldsbase = &As[(size_t)(w * 4 + it) * 64 * 8];
            async_copy16(ldsbase, gA + (size_t)row * KDIM + c * 8);
            bf16* ldsbaseB = &Bs[(size_t)(w * 4 + it) * 64 * 8];
            async_copy16(ldsbaseB, gB + (size_t)row * KDIM + c * 8);
        }
        __syncthreads();
        bf16x8 af[4][2], bb[4][2];
        for (int tm = 0; tm < 4; ++tm)
            for (int ks = 0; ks < 2; ++ks) {
                int r = 64 * wm + 16 * tm + ln;
                af[tm][ks] = *(const bf16x8*)&As[r * 64 + (((ks * 4 + quad) ^ sw) * 8)];
            }
        for (int tn = 0; tn < 4; ++tn)
            for (int ks = 0; ks < 2; ++ks) {
                int r = 64 * wn + 16 * tn + ln;
                bb[tn][ks] = *(const bf16x8*)&Bs[r * 64 + (((ks * 4 + quad) ^ sw) * 8)];
            }
        for (int tm = 0; tm < 4; ++tm)
            for (int tn = 0; tn < 4; ++tn) {
                acc[tm][tn] = __builtin_amdgcn_mfma_f32_16x16x32_bf16(af[tm][0], bb[tn][0], acc[tm][tn], 0, 0, 0);
                acc[tm][tn] = __builtin_amdgcn_mfma_f32_16x16x32_bf16(af[tm][1], bb[tn][1], acc[tm][tn], 0, 0, 0);
            }
    }

    float g = gamma[0];
    float bv[4];
    for (int tn = 0; tn < 4; ++tn) bv[tn] = bp[o0 + 64 * wn + 16 * tn + ln];
    int bidx = (pix0 + 64 * wm) >> 6;   // wave's 64 pix rows are one batch
    float sum = 0.f, ss = 0.f;
    for (int tm = 0; tm < 4; ++tm)
        for (int r = 0; r < 4; ++r) {
            int pixr = pix0 + 64 * wm + 16 * tm + quad * 4 + r;
            int hw = pixr & 63;
            for (int tn = 0; tn < 4; ++tn) {
                int col = o0 + 64 * wn + 16 * tn + ln;
                float v = acc[tm][tn][r] + bv[tn];
                float res = x[((size_t)bidx * CH + col) * HW + hw];
                v = g * v + (1.0f - g) * res;
                out_ws[(size_t)pixr * CH + col] = v;
                sum += v;
                ss += v * v;
            }
        }
    for (int mask = 1; mask < 64; mask <<= 1) {
        sum += __shfl_xor(sum, mask);
        ss  += __shfl_xor(ss, mask);
    }
    if (lane == 0) {
        atomicAdd(&stats[2 * bidx], sum);
        atomicAdd(&stats[2 * bidx + 1], ss);
    }
}

// ---------------- LayerNorm finalize ----------------
__global__ void ln_kernel(const float* __restrict__ out_ws, const float* __restrict__ stats,
                          const float* __restrict__ lnw, const float* __restrict__ lnb,
                          float* __restrict__ y) {
    const size_t total = (size_t)BATCH * CH * HW;
    const float invN = 1.0f / (float)(CH * HW);
    for (size_t i = (size_t)blockIdx.x * 256 + threadIdx.x; i < total; i += (size_t)gridDim.x * 256) {
        int b = (int)(i >> 16);
        int rem = (int)(i & 65535);
        int c = rem >> 6;
        int hw = rem & 63;
        float mean = stats[2 * b] * invN;
        float var = stats[2 * b + 1] * invN - mean * mean;
        float rstd = rsqrtf(var + LN_EPS);
        float v = out_ws[((size_t)(b * HW + hw)) * CH + c];
        y[i] = (v - mean) * rstd * lnw[rem] + lnb[rem];
    }
}

// ---------------- launch ----------------
extern "C" void kernel_launch(void* const* d_in, const int* in_sizes, int n_in,
                              void* d_out, int out_size, void* d_ws, size_t ws_size,
                              hipStream_t stream) {
    const float* x     = (const float*)d_in[0];
    const float* Wq    = (const float*)d_in[1];
    const float* bq    = (const float*)d_in[2];
    const float* Wk    = (const float*)d_in[3];
    const float* bk    = (const float*)d_in[4];
    const float* Wv    = (const float*)d_in[5];
    const float* bv    = (const float*)d_in[6];
    const float* Wp    = (const float*)d_in[7];
    const float* bp    = (const float*)d_in[8];
    const float* gamma = (const float*)d_in[9];
    const float* temp  = (const float*)d_in[10];
    const float* lnw   = (const float*)d_in[11];
    const float* lnb   = (const float*)d_in[12];
    float* y = (float*)d_out;

    char* ws = (char*)d_ws;
    // workspace layout (bytes)
    const size_t off_wqkv = 0;                               // 3072*1024*2 = 6291456
    const size_t off_wp   = 6291456;                         // 1024*1024*2 = 2097152
    const size_t off_bias = off_wp + 2097152;                // 3072*4 = 12288
    const size_t off_stat = off_bias + 12288;                // 1024*2*4 = 8192
    const size_t off_xT   = off_stat + 8192;                 // 65536*1024*2 = 134217728
    const size_t off_qkv  = off_xT + 134217728;              // 65536*3072*2 = 402653184
    const size_t off_ao   = off_qkv + 402653184;             // 65536*1024*2 = 134217728
    const size_t off_out  = off_qkv;                         // alias: qkv dead after attention

    bf16*  wqkv_b = (bf16*)(ws + off_wqkv);
    bf16*  wp_b   = (bf16*)(ws + off_wp);
    float* bias_q = (float*)(ws + off_bias);
    float* stats  = (float*)(ws + off_stat);
    bf16*  xT     = (bf16*)(ws + off_xT);
    bf16*  qkv    = (bf16*)(ws + off_qkv);
    bf16*  ao     = (bf16*)(ws + off_ao);
    float* out_ws = (float*)(ws + off_out);

    const int wn = 1024 * 1024;
    cvt_f32_bf16<<<4096, 256, 0, stream>>>(Wq, wqkv_b, wn);
    cvt_f32_bf16<<<4096, 256, 0, stream>>>(Wk, wqkv_b + (size_t)wn, wn);
    cvt_f32_bf16<<<4096, 256, 0, stream>>>(Wv, wqkv_b + (size_t)2 * wn, wn);
    cvt_f32_bf16<<<4096, 256, 0, stream>>>(Wp, wp_b, wn);
    pack_bias<<<12, 256, 0, stream>>>(bq, bk, bv, bias_q);
    transpose_x<<<dim3(32, 1024), 256, 0, stream>>>(x, xT);
    gemm_qkv<<<dim3(24, 512), 256, 0, stream>>>(xT, wqkv_b, bias_q, qkv);
    attn_kernel<<<dim3(16, 1024), 256, 0, stream>>>(qkv, ao, temp);
    hipMemsetAsync(stats, 0, 8192, stream);
    gemm_proj<<<dim3(8, 512), 256, 0, stream>>>(ao, wp_b, bp, x, gamma, out_ws, stats);
    ln_kernel<<<32768, 256, 0, stream>>>(out_ws, stats, lnw, lnb, y);
}